// Round 11
// baseline (11444.478 us; speedup 1.0000x reference)
//
#include <hip/hip_runtime.h>

// ---------------- constants ----------------
#define NS   256
#define NB   128   // 2 samples per block, lane-split within each wave
#define TS   64
#define DS   32
#define DA   8
#define DD   512
#define HH   8
#define HD   64
#define FF   2048
#define INPP 20
#define INPG 24
#define DP   256
#define KVKP 276
#define KVKPP 280
#define KVO  1032
#define FFP  1024

// packed-weight ws offsets (uint elements, after 128-uint header)
// layout: [KPpad/8][Dout][8]
#define OFF_ODE 0
#define SZ_ODE  (32*512*8)
#define OFF_KV  (OFF_ODE+SZ_ODE)
#define SZ_KV   (35*1032*8)
#define OFF_IN  (OFF_KV+SZ_KV)
#define SZ_IN   (3*512*8)
#define OFF_Q   (OFF_IN+SZ_IN)
#define SZ_Q    (32*512*8)
#define OFF_OUT (OFF_Q+SZ_Q)
#define SZ_OUT  (32*512*8)
#define OFF_F1  (OFF_OUT+SZ_OUT)
#define SZ_F1   (32*2048*8)
#define OFF_F2  (OFF_F1+SZ_F1)
#define SZ_F2   (128*512*8)
#define OFF_DEC (OFF_F2+SZ_F2)
#define SZ_DEC  (32*32*8)

#define DEV __device__ __forceinline__

typedef _Float16 half2_t __attribute__((ext_vector_type(2)));

DEV half2_t as_h2(unsigned int u) { return __builtin_bit_cast(half2_t, u); }

DEV float dot2f(unsigned int w, unsigned int x, float acc) {
#if __has_builtin(__builtin_amdgcn_fdot2)
  return __builtin_amdgcn_fdot2(as_h2(w), as_h2(x), acc, false);
#else
  half2_t a = as_h2(w), b = as_h2(x);
  return acc + (float)a[0] * (float)b[0] + (float)a[1] * (float)b[1];
#endif
}

DEV unsigned int pack2f(float a, float b) {
  unsigned short ua = __builtin_bit_cast(unsigned short, (_Float16)a);
  unsigned short ub = __builtin_bit_cast(unsigned short, (_Float16)b);
  return ((unsigned int)ub << 16) | (unsigned int)ua;
}

DEV float fast_tanh(float x) {
  float ax = fabsf(x);
  float e  = __expf(-2.0f * ax);
  float r  = (1.0f - e) / (1.0f + e);
  return copysignf(r, x);
}

DEV float fast_sigmoid(float x) { return 1.0f / (1.0f + __expf(-x)); }

#define LD4(p) (*reinterpret_cast<const uint4*>(p))

// single-sample grouped packed matvec (column dot, full K)
DEV float dotM(const unsigned int* __restrict__ Wc, int strideG,
               const unsigned int* __restrict__ xq, int NG, float init) {
  float a0 = init, a1 = 0.f, a2 = 0.f, a3 = 0.f;
  #pragma unroll 4
  for (int g = 0; g < NG; ++g) {
    uint4 w0 = LD4(Wc + g * strideG);
    uint4 w1 = LD4(Wc + g * strideG + 4);
    uint4 x0 = LD4(xq + g * 8);
    uint4 x1 = LD4(xq + g * 8 + 4);
    a0 = dot2f(w0.x, x0.x, a0); a1 = dot2f(w0.y, x0.y, a1);
    a2 = dot2f(w0.z, x0.z, a2); a3 = dot2f(w0.w, x0.w, a3);
    a0 = dot2f(w1.x, x1.x, a0); a1 = dot2f(w1.y, x1.y, a1);
    a2 = dot2f(w1.z, x1.z, a2); a3 = dot2f(w1.w, x1.w, a3);
  }
  return (a0 + a1) + (a2 + a3);
}

// ---------------- weight f32 -> grouped packed f16 pairs ----------------
__global__ void pack_wg_kernel(const float* __restrict__ src, unsigned int* __restrict__ dst,
                               int K, int KPpad, int Dout) {
  int idx = blockIdx.x * blockDim.x + threadIdx.x;
  int total = KPpad * Dout;
  if (idx >= total) return;
  int kp = idx / Dout;
  int j  = idx - kp * Dout;
  int r0 = 2 * kp, r1 = r0 + 1;
  float lo = (r0 < K) ? src[r0 * Dout + j] : 0.f;
  float hi = (r1 < K) ? src[r1 * Dout + j] : 0.f;
  int kg = kp >> 3, sub = kp & 7;
  dst[((kg * Dout + j) << 3) + sub] = pack2f(lo, hi);
}

// ---------------- main: 1024 thr, 2 samples lane-split within each wave ----------------
// M1 (weight matvecs): s1 = lane>>5, mcol = w*32 + (lane&31)
//   -> lanes 0-31 and 32-63 load IDENTICAL weight addresses (coalesced once),
//      dot against their own sample's x. Weight bytes fetched once feed 2 samples.
// M2 (elementwise/softmax/pack/fw-update): s2 = tid>>9, c2 = tid&511 (R2 code + [s] index).
__global__ __launch_bounds__(1024, 4) void fwp_main(
    const float* __restrict__ states, const float* __restrict__ actions,
    const float* __restrict__ tsteps,
    const float* __restrict__ b_ode, const float* __restrict__ b_in,
    const float* __restrict__ ln_in_g, const float* __restrict__ ln_in_b,
    const float* __restrict__ b_q, const float* __restrict__ b_kv,
    const float* __restrict__ b_out,
    const float* __restrict__ ln_ff_g, const float* __restrict__ ln_ff_b,
    const float* __restrict__ b_ff1, const float* __restrict__ b_ff2,
    const float* __restrict__ b_dec,
    const unsigned int* __restrict__ Wode, const unsigned int* __restrict__ Wkv,
    const unsigned int* __restrict__ Win,  const unsigned int* __restrict__ Wq,
    const unsigned int* __restrict__ Wout, const unsigned int* __restrict__ Wff1,
    const unsigned int* __restrict__ Wff2, const unsigned int* __restrict__ Wdec,
    unsigned int* __restrict__ ctrs, float* __restrict__ outp) {

  const int b = blockIdx.x, tid = threadIdx.x;
  const int w = tid >> 6, lane = tid & 63;
  const int s1 = lane >> 5;                 // matvec sample
  const int mcol = w * 32 + (lane & 31);    // matvec column 0..511
  const int s2 = tid >> 9;                  // elementwise sample
  const int c2 = tid & 511;                 // elementwise column 0..511
  const int n0 = 2 * b;
  const int strideG = DD * 8;

  __shared__ alignas(16) float        sh_h[2][DD];
  __shared__ alignas(16) unsigned int sh_hp[2][DP];
  __shared__ alignas(16) unsigned int sh_xp[2][KVKPP];
  __shared__ alignas(16) unsigned int sh_dp[2][INPG];
  __shared__ alignas(16) float        sh_t[2][DD];
  __shared__ alignas(16) unsigned int sh_p[2][DP];
  __shared__ alignas(16) float        sh_kvb[2][KVO];
  __shared__ alignas(16) float        sh_k[2][DD];
  __shared__ alignas(16) float        sh_v[2][DD];
  __shared__ alignas(16) float        sh_q[2][DD];
  __shared__ float                    sh_lr[2][HH];
  __shared__ alignas(16) float        sh_ff[2][FF];
  __shared__ alignas(16) unsigned int sh_ffp[2][FFP];
  __shared__ float                    sh_red[2][32];
  __shared__ alignas(16) float        sh_decp[2][512];
  __shared__ int                      sh_flag;

  // fast-weight state: (sample=s2, head=c2>>6, row=c2&63) -> 64 f32/thread
  float W2r[64];
  #pragma unroll
  for (int i = 0; i < 64; ++i) W2r[i] = 0.f;

  sh_h[s2][c2] = 0.f;
  if (c2 < DP) sh_hp[s2][c2] = 0u;
  if (c2 < (KVKPP - KVKP)) sh_xp[s2][KVKP + c2] = 0u;
  if (c2 < (INPG - INPP))  sh_dp[s2][INPP + c2] = 0u;

  bool pace = true;
  unsigned int* ctr = ctrs + 16 * (b & 7);   // 16 blocks per counter group

  for (int t = 0; t < TS; ++t) {
    __syncthreads();

    // ---- loose pacing barrier (bounded spin; perf-only, deadlock-free)
    if (pace) {
      if (tid == 0) {
        sh_flag = 0;
        __hip_atomic_fetch_add(ctr, 1u, __ATOMIC_RELAXED, __HIP_MEMORY_SCOPE_AGENT);
        unsigned int tgt = 16u * (unsigned int)(t + 1);
        int it = 0;
        while (__hip_atomic_load(ctr, __ATOMIC_RELAXED, __HIP_MEMORY_SCOPE_AGENT) < tgt) {
          if (++it > 4096) { sh_flag = 1; break; }
          __builtin_amdgcn_s_sleep(8);
        }
      }
      __syncthreads();
      if (sh_flag) pace = false;
    }

    // ---- inputs (both samples) & dts
    if (c2 < INPP) {
      int n = n0 + s2;
      int i0 = 2 * c2, i1 = i0 + 1;
      float a = (i0 < DS) ? states[(n * TS + t) * DS + i0] : actions[(n * TS + t) * DA + (i0 - DS)];
      float c = (i1 < DS) ? states[(n * TS + t) * DS + i1] : actions[(n * TS + t) * DA + (i1 - DS)];
      unsigned int p = pack2f(a, c);
      sh_xp[s2][c2] = p;
      sh_dp[s2][c2] = p;
    }
    const float sdtA = 0.25f * (tsteps[n0 * (TS + 1) + t + 1] - tsteps[n0 * (TS + 1) + t]);
    const float sdtB = 0.25f * (tsteps[(n0 + 1) * (TS + 1) + t + 1] - tsteps[(n0 + 1) * (TS + 1) + t]);
    const float sdt_s = s1 ? sdtB : sdtA;

    // ---- ODE: 4 Euler steps (M1)
    for (int e = 0; e < 4; ++e) {
      float acc = dotM(Wode + mcol * 8, strideG, sh_hp[s1], 32, b_ode[mcol]);
      sh_h[s1][mcol] += sdt_s * fast_tanh(acc);
      __syncthreads();
      if (c2 < DP) sh_hp[s2][c2] = pack2f(sh_h[s2][2 * c2], sh_h[s2][2 * c2 + 1]);
      __syncthreads();
    }

    // ---- x = [data, h1]
    if (c2 < DP) sh_xp[s2][INPP + c2] = sh_hp[s2][c2];
    __syncthreads();

    // ---- kv = x @ W_kv + b_kv (1032 cols; M1, 2 cols/thread + tail)
    {
      sh_kvb[s1][mcol]       = dotM(Wkv + mcol * 8,         KVO * 8, sh_xp[s1], 35, b_kv[mcol]);
      sh_kvb[s1][mcol + 512] = dotM(Wkv + (mcol + 512) * 8, KVO * 8, sh_xp[s1], 35, b_kv[mcol + 512]);
      if (mcol < 8)
        sh_kvb[s1][mcol + 1024] = dotM(Wkv + (mcol + 1024) * 8, KVO * 8, sh_xp[s1], 35, b_kv[mcol + 1024]);
    }
    __syncthreads();

    // ---- k = softmax(head), v = tanh, lr = sigmoid (M2; wave = one head of one sample)
    {
      float kx = sh_kvb[s2][c2];
      float km = kx;
      #pragma unroll
      for (int o = 32; o; o >>= 1) km = fmaxf(km, __shfl_xor(km, o));
      float ke = __expf(kx - km);
      float ks = ke;
      #pragma unroll
      for (int o = 32; o; o >>= 1) ks += __shfl_xor(ks, o);
      sh_k[s2][c2] = ke / ks;
      sh_v[s2][c2] = fast_tanh(sh_kvb[s2][DD + c2]);
      if (c2 < HH) sh_lr[s2][c2] = fast_sigmoid(sh_kvb[s2][2 * DD + c2]);
    }

    // ---- q path: y1 = data @ W_in + b_in (M1), then LN over 512 cols per sample
    {
      float y1 = dotM(Win + mcol * 8, strideG, sh_dp[s1], 3, b_in[mcol]);
      float ss = y1, sq = y1 * y1;
      #pragma unroll
      for (int o = 16; o; o >>= 1) { ss += __shfl_xor(ss, o); sq += __shfl_xor(sq, o); }
      if ((lane & 31) == 0) { sh_red[s1][2 * w] = ss; sh_red[s1][2 * w + 1] = sq; }
      __syncthreads();
      float t1 = 0.f, t2 = 0.f;
      #pragma unroll
      for (int i = 0; i < 16; ++i) { t1 += sh_red[s1][2 * i]; t2 += sh_red[s1][2 * i + 1]; }
      float m  = t1 * (1.0f / DD);
      float va = fmaxf(t2 * (1.0f / DD) - m * m, 0.f);
      float rs = rsqrtf(va + 1e-5f);
      sh_t[s1][mcol] = (y1 - m) * rs * ln_in_g[mcol] + ln_in_b[mcol];
    }
    __syncthreads();
    if (c2 < DP) sh_p[s2][c2] = pack2f(sh_t[s2][2 * c2], sh_t[s2][2 * c2 + 1]);
    __syncthreads();

    // ---- qraw = LN @ W_q + b_q (M1) -> LDS -> per-head softmax (M2)
    sh_t[s1][mcol] = dotM(Wq + mcol * 8, strideG, sh_p[s1], 32, b_q[mcol]);
    __syncthreads();
    {
      float qt = sh_t[s2][c2];
      float qm = qt;
      #pragma unroll
      for (int o = 32; o; o >>= 1) qm = fmaxf(qm, __shfl_xor(qm, o));
      float qe = __expf(qt - qm);
      float qs = qe;
      #pragma unroll
      for (int o = 32; o; o >>= 1) qs += __shfl_xor(qs, o);
      sh_q[s2][c2] = qe / qs;
    }
    __syncthreads();

    // ---- fused fast-weight update + query (M2)
    {
      int head = c2 >> 6;
      float lv = sh_lr[s2][head] * sh_v[s2][c2];
      float acc = 0.f;
      const float* kb = sh_k[s2] + head * HD;
      const float* qb = sh_q[s2] + head * HD;
      #pragma unroll
      for (int jc = 0; jc < 16; ++jc) {
        float4 k4 = *reinterpret_cast<const float4*>(kb + 4 * jc);
        float4 q4 = *reinterpret_cast<const float4*>(qb + 4 * jc);
        W2r[4 * jc + 0] += lv * k4.x; acc += W2r[4 * jc + 0] * q4.x;
        W2r[4 * jc + 1] += lv * k4.y; acc += W2r[4 * jc + 1] * q4.y;
        W2r[4 * jc + 2] += lv * k4.z; acc += W2r[4 * jc + 2] * q4.z;
        W2r[4 * jc + 3] += lv * k4.w; acc += W2r[4 * jc + 3] * q4.w;
      }
      sh_t[s2][c2] = acc;
    }
    __syncthreads();
    if (c2 < DP) sh_p[s2][c2] = pack2f(sh_t[s2][2 * c2], sh_t[s2][2 * c2 + 1]);
    __syncthreads();

    // ---- out1 = out @ W_out + b_out (M1) + LN_ff
    float o1 = dotM(Wout + mcol * 8, strideG, sh_p[s1], 32, b_out[mcol]);
    {
      float ss = o1, sq = o1 * o1;
      #pragma unroll
      for (int o = 16; o; o >>= 1) { ss += __shfl_xor(ss, o); sq += __shfl_xor(sq, o); }
      if ((lane & 31) == 0) { sh_red[s1][2 * w] = ss; sh_red[s1][2 * w + 1] = sq; }
      __syncthreads();
      float t1 = 0.f, t2 = 0.f;
      #pragma unroll
      for (int i = 0; i < 16; ++i) { t1 += sh_red[s1][2 * i]; t2 += sh_red[s1][2 * i + 1]; }
      float m  = t1 * (1.0f / DD);
      float va = fmaxf(t2 * (1.0f / DD) - m * m, 0.f);
      float rs = rsqrtf(va + 1e-5f);
      sh_t[s1][mcol] = (o1 - m) * rs * ln_ff_g[mcol] + ln_ff_b[mcol];
    }
    __syncthreads();
    if (c2 < DP) sh_p[s2][c2] = pack2f(sh_t[s2][2 * c2], sh_t[s2][2 * c2 + 1]);
    __syncthreads();

    // ---- FF1 + relu (M1: 4 cols/thread, fused K-loop)
    {
      float f0 = b_ff1[mcol];
      float f1 = b_ff1[mcol + 512];
      float f2 = b_ff1[mcol + 1024];
      float f3 = b_ff1[mcol + 1536];
      #pragma unroll 2
      for (int g = 0; g < 32; ++g) {
        const unsigned int* wb = Wff1 + g * (FF * 8) + mcol * 8;
        uint4 wa0 = LD4(wb);
        uint4 wa1 = LD4(wb + 4);
        uint4 wb0 = LD4(wb + 512 * 8);
        uint4 wb1 = LD4(wb + 512 * 8 + 4);
        uint4 wc0 = LD4(wb + 1024 * 8);
        uint4 wc1 = LD4(wb + 1024 * 8 + 4);
        uint4 wd0 = LD4(wb + 1536 * 8);
        uint4 wd1 = LD4(wb + 1536 * 8 + 4);
        uint4 x0 = LD4(sh_p[s1] + g * 8);
        uint4 x1 = LD4(sh_p[s1] + g * 8 + 4);
        f0 = dot2f(wa0.x, x0.x, f0); f0 = dot2f(wa0.y, x0.y, f0);
        f0 = dot2f(wa0.z, x0.z, f0); f0 = dot2f(wa0.w, x0.w, f0);
        f0 = dot2f(wa1.x, x1.x, f0); f0 = dot2f(wa1.y, x1.y, f0);
        f0 = dot2f(wa1.z, x1.z, f0); f0 = dot2f(wa1.w, x1.w, f0);
        f1 = dot2f(wb0.x, x0.x, f1); f1 = dot2f(wb0.y, x0.y, f1);
        f1 = dot2f(wb0.z, x0.z, f1); f1 = dot2f(wb0.w, x0.w, f1);
        f1 = dot2f(wb1.x, x1.x, f1); f1 = dot2f(wb1.y, x1.y, f1);
        f1 = dot2f(wb1.z, x1.z, f1); f1 = dot2f(wb1.w, x1.w, f1);
        f2 = dot2f(wc0.x, x0.x, f2); f2 = dot2f(wc0.y, x0.y, f2);
        f2 = dot2f(wc0.z, x0.z, f2); f2 = dot2f(wc0.w, x0.w, f2);
        f2 = dot2f(wc1.x, x1.x, f2); f2 = dot2f(wc1.y, x1.y, f2);
        f2 = dot2f(wc1.z, x1.z, f2); f2 = dot2f(wc1.w, x1.w, f2);
        f3 = dot2f(wd0.x, x0.x, f3); f3 = dot2f(wd0.y, x0.y, f3);
        f3 = dot2f(wd0.z, x0.z, f3); f3 = dot2f(wd0.w, x0.w, f3);
        f3 = dot2f(wd1.x, x1.x, f3); f3 = dot2f(wd1.y, x1.y, f3);
        f3 = dot2f(wd1.z, x1.z, f3); f3 = dot2f(wd1.w, x1.w, f3);
      }
      sh_ff[s1][mcol]        = fmaxf(f0, 0.f);
      sh_ff[s1][mcol + 512]  = fmaxf(f1, 0.f);
      sh_ff[s1][mcol + 1024] = fmaxf(f2, 0.f);
      sh_ff[s1][mcol + 1536] = fmaxf(f3, 0.f);
    }
    __syncthreads();
    sh_ffp[s2][c2]       = pack2f(sh_ff[s2][2 * c2], sh_ff[s2][2 * c2 + 1]);
    sh_ffp[s2][c2 + 512] = pack2f(sh_ff[s2][1024 + 2 * c2], sh_ff[s2][1025 + 2 * c2]);
    __syncthreads();

    // ---- FF2 + bias + residual -> new h1 (M1, 128 groups)
    {
      float o2 = dotM(Wff2 + mcol * 8, strideG, sh_ffp[s1], 128, b_ff2[mcol]);
      sh_h[s1][mcol] = o2 + o1;
    }
    __syncthreads();
    if (c2 < DP) sh_hp[s2][c2] = pack2f(sh_h[s2][2 * c2], sh_h[s2][2 * c2 + 1]);
    __syncthreads();

    // ---- decoder (M2: 32 cols x 16 chunks of 2 groups, per sample)
    {
      int colD = c2 & 31, ch = c2 >> 5;
      const unsigned int* wbse = Wdec + colD * 8;
      float a = 0.f;
      #pragma unroll
      for (int g = 2 * ch; g < 2 * ch + 2; ++g) {
        uint4 w0 = LD4(wbse + g * (DS * 8));
        uint4 w1 = LD4(wbse + g * (DS * 8) + 4);
        uint4 x0 = LD4(sh_hp[s2] + g * 8);
        uint4 x1 = LD4(sh_hp[s2] + g * 8 + 4);
        a = dot2f(w0.x, x0.x, a); a = dot2f(w0.y, x0.y, a);
        a = dot2f(w0.z, x0.z, a); a = dot2f(w0.w, x0.w, a);
        a = dot2f(w1.x, x1.x, a); a = dot2f(w1.y, x1.y, a);
        a = dot2f(w1.z, x1.z, a); a = dot2f(w1.w, x1.w, a);
      }
      sh_decp[s2][c2] = a;
    }
    __syncthreads();
    if (c2 < DS) {
      float s = b_dec[c2];
      #pragma unroll
      for (int c = 0; c < 16; ++c) s += sh_decp[s2][c * 32 + c2];
      outp[((n0 + s2) * TS + t) * DS + c2] = s;
    }
  }
}

// ---------------- host launcher ----------------
extern "C" void kernel_launch(void* const* d_in, const int* in_sizes, int n_in,
                              void* d_out, int out_size, void* d_ws, size_t ws_size,
                              hipStream_t stream) {
  (void)in_sizes; (void)n_in; (void)out_size; (void)ws_size;

  const float* states   = (const float*)d_in[0];
  const float* actions  = (const float*)d_in[1];
  const float* tsteps   = (const float*)d_in[2];
  const float* W_ode    = (const float*)d_in[3];
  const float* b_ode    = (const float*)d_in[4];
  const float* W_in     = (const float*)d_in[5];
  const float* b_in     = (const float*)d_in[6];
  const float* ln_in_g  = (const float*)d_in[7];
  const float* ln_in_b  = (const float*)d_in[8];
  const float* W_q      = (const float*)d_in[9];
  const float* b_q      = (const float*)d_in[10];
  const float* W_kv     = (const float*)d_in[11];
  const float* b_kv     = (const float*)d_in[12];
  const float* W_out    = (const float*)d_in[13];
  const float* b_out    = (const float*)d_in[14];
  const float* ln_ff_g  = (const float*)d_in[15];
  const float* ln_ff_b  = (const float*)d_in[16];
  const float* W_ff1    = (const float*)d_in[17];
  const float* b_ff1    = (const float*)d_in[18];
  const float* W_ff2    = (const float*)d_in[19];
  const float* b_ff2    = (const float*)d_in[20];
  const float* W_dec    = (const float*)d_in[21];
  const float* b_dec    = (const float*)d_in[22];

  unsigned int* wsbase = (unsigned int*)d_ws;
  unsigned int* ctrs   = wsbase;           // 8 counters, 64B apart (512B region)
  unsigned int* W      = wsbase + 128;     // packed weights

  hipMemsetAsync(d_ws, 0, 512, stream);

  auto launch_pack = [&](const float* src, unsigned int* dst, int K, int KPpad, int Dout) {
    int total = KPpad * Dout;
    int blocks = (total + 255) / 256;
    pack_wg_kernel<<<blocks, 256, 0, stream>>>(src, dst, K, KPpad, Dout);
  };

  launch_pack(W_ode, W + OFF_ODE, 512,  256, 512);
  launch_pack(W_kv,  W + OFF_KV,  552,  280, 1032);
  launch_pack(W_in,  W + OFF_IN,  40,   24,  512);
  launch_pack(W_q,   W + OFF_Q,   512,  256, 512);
  launch_pack(W_out, W + OFF_OUT, 512,  256, 512);
  launch_pack(W_ff1, W + OFF_F1,  512,  256, 2048);
  launch_pack(W_ff2, W + OFF_F2,  2048, 1024, 512);
  launch_pack(W_dec, W + OFF_DEC, 512,  256, 32);

  fwp_main<<<NB, 1024, 0, stream>>>(
      states, actions, tsteps,
      b_ode, b_in, ln_in_g, ln_in_b, b_q, b_kv, b_out, ln_ff_g, ln_ff_b,
      b_ff1, b_ff2, b_dec,
      W + OFF_ODE, W + OFF_KV, W + OFF_IN, W + OFF_Q,
      W + OFF_OUT, W + OFF_F1, W + OFF_F2, W + OFF_DEC,
      ctrs, (float*)d_out);
}